// Round 11
// baseline (370.265 us; speedup 1.0000x reference)
//
#include <hip/hip_runtime.h>
#include <math.h>

#define EPSF 1e-8f
#define LOG2E 1.44269504f

typedef short short8 __attribute__((ext_vector_type(8)));
typedef float floatx4 __attribute__((ext_vector_type(4)));

__device__ __forceinline__ unsigned short f2bf(float f) {
    unsigned u = __builtin_bit_cast(unsigned, f);
    unsigned r = (u + 0x7FFFu + ((u >> 16) & 1u)) >> 16;   // RNE
    return (unsigned short)r;
}
__device__ __forceinline__ float bf2f(unsigned short h) {
    return __builtin_bit_cast(float, ((unsigned)h) << 16);
}

// Raw v_exp_f32 where available: args are always <= 0, and weights below 2^-126
// are ~0 either way, so libm's denorm-fixup wrapper is dead weight.
__device__ __forceinline__ float fast_exp2(float x) {
#if __has_builtin(__builtin_amdgcn_exp2f)
    return __builtin_amdgcn_exp2f(x);
#else
    return exp2f(x);
#endif
}

// ---- Prep (one launch, no atomics):
//  blocks 0..31          : train -> bf16 hi/lo + tnorm
//  blocks 32..32+m/256-1 : qn (query norms)
//  last block            : full column stats (fp64) + Scott finalize -> sCws
// The stats block re-reads train (1 MB, L2-hot) and runs concurrently with the
// staging blocks on idle CUs -- no launch bubble, no cross-block sync.
__global__ __launch_bounds__(256) void prep_kernel(const float* __restrict__ x,
                                                   const float* __restrict__ train,
                                                   int n, int m,
                                                   float* __restrict__ tnorm,
                                                   float* __restrict__ qn,
                                                   unsigned short* __restrict__ thi,
                                                   unsigned short* __restrict__ tlo,
                                                   float* __restrict__ sCws) {
    int tid = threadIdx.x;
    int b = blockIdx.x;
    if (b < 32) {
        int rowsPerBlock = n >> 5;          // 256
        int rbase = b * rowsPerBlock;
        for (int r = rbase + tid; r < rbase + rowsPerBlock; r += 256) {
            const float4* row = (const float4*)(train + (size_t)r * 32);
            float s = 0.f;
#pragma unroll
            for (int kb = 0; kb < 4; ++kb) {
                float4 f0 = row[kb * 2], f1 = row[kb * 2 + 1];
                float fv[8] = {f0.x, f0.y, f0.z, f0.w, f1.x, f1.y, f1.z, f1.w};
                short8 h, l;
#pragma unroll
                for (int j = 0; j < 8; ++j) {
                    unsigned short hb = f2bf(fv[j]);
                    h[j] = (short)hb;
                    l[j] = (short)f2bf(fv[j] - bf2f(hb));
                    s = fmaf(fv[j], fv[j], s);
                }
                *(short8*)(thi + (size_t)r * 32 + kb * 8) = h;
                *(short8*)(tlo + (size_t)r * 32 + kb * 8) = l;
            }
            tnorm[r] = s;
        }
    } else {
        int r = (b - 32) * 256 + tid;
        if (r < m) {
            const float4* row = (const float4*)(x + (size_t)r * 32);
            float s = 0.f;
#pragma unroll
            for (int k = 0; k < 8; ++k) {
                float4 t = row[k];
                s = fmaf(t.x, t.x, s); s = fmaf(t.y, t.y, s);
                s = fmaf(t.z, t.z, s); s = fmaf(t.w, t.w, s);
            }
            qn[r] = s;
        } else if (b == (int)gridDim.x - 1) {
            // ---- dedicated Scott block: full column sums, no partials ----
            __shared__ double s1s[256];
            __shared__ double s2s[256];
            __shared__ float sdv[32];
            int dim = tid & 31;
            int grp = tid >> 5;
            int rpt = n >> 3;               // 1024 rows per group
            int r0 = grp * rpt;
            double s1 = 0.0, s2 = 0.0;
            for (int i = 0; i < rpt; ++i) {
                double v = (double)train[(size_t)(r0 + i) * 32 + dim];
                s1 += v;
                s2 += v * v;
            }
            s1s[tid] = s1;
            s2s[tid] = s2;
            __syncthreads();
            if (tid < 32) {
                double a = 0.0, c2 = 0.0;
                for (int g = 0; g < 8; ++g) { a += s1s[g * 32 + tid]; c2 += s2s[g * 32 + tid]; }
                double var = (c2 - a * a / (double)n) / (double)(n - 1);  // ddof=1
                sdv[tid] = (float)sqrt(var);
            }
            __syncthreads();
            if (tid == 0) {
                float ms = 0.f;
                for (int k = 0; k < 32; ++k) ms += sdv[k];
                ms *= (1.0f / 32.0f);
                float bw = ms * powf((float)n, -1.0f / 36.0f);
                float c = 1.0f / (2.0f * bw * bw);
                sCws[0] = -c * LOG2E;        // negcl
                sCws[1] = 2.0f * c * LOG2E;  // C2
            }
        }
    }
}

// ---- KDE via MFMA: 2-term bf16 split, M=32/wave, N-tiles of 16, K=32 in one MFMA ----
// R7-proven form (49.2 us): scalar epilogue, unroll 4, launch_bounds(256,8), VGPR 32.
__global__ __launch_bounds__(256, 8) void kde_kernel(const float* __restrict__ x,
                                                     const unsigned short* __restrict__ thi,
                                                     const unsigned short* __restrict__ tlo,
                                                     const float* __restrict__ resid,
                                                     const float* __restrict__ tnorm,
                                                     const float* __restrict__ qn,
                                                     const float* __restrict__ sCws,
                                                     int m, int n, int nchunks,
                                                     float* __restrict__ numP,
                                                     float* __restrict__ denP) {
    int tid = threadIdx.x;
    float negcl = sCws[0], C2 = sCws[1];   // uniform -> scalar loads

    int lane = tid & 63;
    int wave = tid >> 6;
    int col = lane & 15;      // A m-index / B n-index / D col
    int quad = lane >> 4;     // D rows = quad*4 + r
    int Mbase = blockIdx.x * 128 + wave * 32;
    int chunk = n / nchunks;
    int Nstart = blockIdx.y * chunk;

    // --- A fragments: queries prescaled by C2 -> bf16 hi/lo, kept in VGPRs ---
    short8 ah[2], al[2];
#pragma unroll
    for (int s = 0; s < 2; ++s) {
        const float* xp = x + (size_t)(Mbase + s * 16 + col) * 32 + quad * 8;
        float4 f0 = *(const float4*)xp;
        float4 f1 = *(const float4*)(xp + 4);
        float fv[8] = {f0.x, f0.y, f0.z, f0.w, f1.x, f1.y, f1.z, f1.w};
#pragma unroll
        for (int j = 0; j < 8; ++j) {
            float v = fv[j] * C2;
            unsigned short hb = f2bf(v);
            ah[s][j] = (short)hb;
            al[s][j] = (short)f2bf(v - bf2f(hb));
        }
    }

    // --- per-row log2-domain query-norm term ---
    float alpha[2][4];
#pragma unroll
    for (int s = 0; s < 2; ++s)
#pragma unroll
        for (int r = 0; r < 4; ++r)
            alpha[s][r] = negcl * qn[Mbase + s * 16 + quad * 4 + r];

    float num[2][4] = {{0.f, 0.f, 0.f, 0.f}, {0.f, 0.f, 0.f, 0.f}};
    float den[2][4] = {{0.f, 0.f, 0.f, 0.f}, {0.f, 0.f, 0.f, 0.f}};

#pragma unroll 4
    for (int t = 0; t < chunk; t += 16) {
        int row = Nstart + t + col;
        const short8 bh = *(const short8*)(thi + (size_t)row * 32 + quad * 8);
        const short8 bl = *(const short8*)(tlo + (size_t)row * 32 + quad * 8);
        float beta = negcl * tnorm[row];   // per-col (lane) train-norm term
        float rv = resid[row];

#pragma unroll
        for (int s = 0; s < 2; ++s) {
            floatx4 acc = {alpha[s][0] + beta, alpha[s][1] + beta,
                           alpha[s][2] + beta, alpha[s][3] + beta};
            acc = __builtin_amdgcn_mfma_f32_16x16x32_bf16(ah[s], bh, acc, 0, 0, 0);
            acc = __builtin_amdgcn_mfma_f32_16x16x32_bf16(ah[s], bl, acc, 0, 0, 0);
            acc = __builtin_amdgcn_mfma_f32_16x16x32_bf16(al[s], bh, acc, 0, 0, 0);
#pragma unroll
            for (int r = 0; r < 4; ++r) {
                float w = fast_exp2(acc[r]);   // arg == acc (log2 domain)
                num[s][r] = fmaf(w, rv, num[s][r]);
                den[s][r] += w;
            }
        }
    }

    // --- reduce across the 16 lanes sharing each row set (xor 1,2,4,8) ---
#pragma unroll
    for (int s = 0; s < 2; ++s)
#pragma unroll
        for (int r = 0; r < 4; ++r) {
#pragma unroll
            for (int msk = 1; msk < 16; msk <<= 1) {
                num[s][r] += __shfl_xor(num[s][r], msk);
                den[s][r] += __shfl_xor(den[s][r], msk);
            }
        }
    if (col == 0) {
#pragma unroll
        for (int s = 0; s < 2; ++s)
#pragma unroll
            for (int r = 0; r < 4; ++r) {
                int q = Mbase + s * 16 + quad * 4 + r;
                numP[(size_t)blockIdx.y * m + q] = num[s][r];
                denP[(size_t)blockIdx.y * m + q] = den[s][r];
            }
    }
}

// ---- Reduce partials -> rx; per-block min/max of rx & sigma (wave-shuffle version) ----
__global__ __launch_bounds__(256) void reduce_kernel(const float* __restrict__ numP,
                                                     const float* __restrict__ denP,
                                                     const float* __restrict__ sigma,
                                                     float* __restrict__ rxbuf,
                                                     float* __restrict__ bred,
                                                     int m, int nchunks, int nb) {
    __shared__ float wred[4][4];   // [quantity][wave]
    int tid = threadIdx.x;
    int q = blockIdx.x * 256 + tid;

    float num = 0.f, den = 0.f;
    for (int s = 0; s < nchunks; ++s) {
        num += numP[(size_t)s * m + q];
        den += denP[(size_t)s * m + q];
    }
    float rx = num / (den + EPSF);
    rxbuf[q] = rx;
    float sg = sigma[q];

    float rmin = rx, rmax = rx, smin = sg, smax = sg;
#pragma unroll
    for (int o = 32; o > 0; o >>= 1) {
        rmin = fminf(rmin, __shfl_xor(rmin, o));
        rmax = fmaxf(rmax, __shfl_xor(rmax, o));
        smin = fminf(smin, __shfl_xor(smin, o));
        smax = fmaxf(smax, __shfl_xor(smax, o));
    }
    int wave = tid >> 6;
    if ((tid & 63) == 0) {
        wred[0][wave] = rmin; wred[1][wave] = rmax;
        wred[2][wave] = smin; wred[3][wave] = smax;
    }
    __syncthreads();
    if (tid == 0) {
        bred[0 * nb + blockIdx.x] = fminf(fminf(wred[0][0], wred[0][1]), fminf(wred[0][2], wred[0][3]));
        bred[1 * nb + blockIdx.x] = fmaxf(fmaxf(wred[1][0], wred[1][1]), fmaxf(wred[1][2], wred[1][3]));
        bred[2 * nb + blockIdx.x] = fminf(fminf(wred[2][0], wred[2][1]), fminf(wred[2][2], wred[2][3]));
        bred[3 * nb + blockIdx.x] = fmaxf(fmaxf(wred[3][0], wred[3][1]), fmaxf(wred[3][2], wred[3][3]));
    }
}

// ---- Combine: each block redundantly reduces the 64 block-extrema, then writes slice ----
__global__ __launch_bounds__(256) void combine_kernel(const float* __restrict__ rxbuf,
                                                      const float* __restrict__ sigma,
                                                      const float* __restrict__ bred,
                                                      float* __restrict__ out,
                                                      int m, int nb) {
    __shared__ float sc[4];
    int tid = threadIdx.x;
    if (tid < 64) {
        float v0 = (tid < nb) ? bred[0 * nb + tid] : INFINITY;
        float v1 = (tid < nb) ? bred[1 * nb + tid] : -INFINITY;
        float v2 = (tid < nb) ? bred[2 * nb + tid] : INFINITY;
        float v3 = (tid < nb) ? bred[3 * nb + tid] : -INFINITY;
        for (int o = 32; o > 0; o >>= 1) {
            v0 = fminf(v0, __shfl_xor(v0, o));
            v1 = fmaxf(v1, __shfl_xor(v1, o));
            v2 = fminf(v2, __shfl_xor(v2, o));
            v3 = fmaxf(v3, __shfl_xor(v3, o));
        }
        if (tid == 0) {
            sc[0] = v0;
            sc[1] = 1.0f / (v1 - v0 + EPSF);
            sc[2] = v2;
            sc[3] = 1.0f / (v3 - v2 + EPSF);
        }
    }
    __syncthreads();
    int q = blockIdx.x * 256 + tid;
    if (q >= m) return;
    float t1 = 0.5f * (rxbuf[q] - sc[0]) * sc[1];
    float t2 = 0.5f * (sigma[q] - sc[2]) * sc[3];
    out[q] = t1 + t2;
}

extern "C" void kernel_launch(void* const* d_in, const int* in_sizes, int n_in,
                              void* d_out, int out_size, void* d_ws, size_t ws_size,
                              hipStream_t stream) {
    const float* x     = (const float*)d_in[0];  // [m, 32]
    const float* train = (const float*)d_in[1];  // [n, 32]
    const float* resid = (const float*)d_in[2];  // [n]
    const float* sigma = (const float*)d_in[3];  // [m]
    float* out = (float*)d_out;

    int n = in_sizes[2];   // 8192
    int m = in_sizes[3];   // 16384
    int nb = m / 256;      // 64

    // ws layout: fp32 arrays, scalar block, bf16 arrays, partials
    float*  tnorm = (float*)d_ws;                   // n
    float*  qn    = tnorm + n;                      // m
    float*  rxbuf = qn + m;                         // m
    float*  bred  = rxbuf + m;                      // 4*nb
    float*  sCws  = bred + 4 * nb;                  // 2 floats + 2 pad
    unsigned short* thi = (unsigned short*)(sCws + 4);       // n*32
    unsigned short* tlo = thi + (size_t)n * 32;              // n*32
    float* numP = (float*)(tlo + (size_t)n * 32);
    size_t baseBytes = (size_t)((char*)numP - (char*)d_ws);

    int nchunks = 16;
    while (nchunks > 1 &&
           baseBytes + (size_t)2 * nchunks * m * sizeof(float) > ws_size)
        nchunks >>= 1;
    float* denP = numP + (size_t)nchunks * m;

    // 4 stream ops total (R10 lesson: each extra op costs ~5-6 us replay overhead)
    int nqb = (m + 255) / 256;
    prep_kernel<<<32 + nqb + 1, 256, 0, stream>>>(x, train, n, m, tnorm, qn,
                                                  thi, tlo, sCws);

    dim3 grid_c(m / 128, nchunks);   // 4 waves/block, M=32 per wave; 2048 blocks = 8/CU resident
    kde_kernel<<<grid_c, 256, 0, stream>>>(x, thi, tlo, resid, tnorm, qn,
                                           sCws, m, n, nchunks, numP, denP);

    reduce_kernel<<<nb, 256, 0, stream>>>(numP, denP, sigma, rxbuf, bred, m, nchunks, nb);
    combine_kernel<<<nb, 256, 0, stream>>>(rxbuf, sigma, bred, out, m, nb);
}

// Round 12
// 179.754 us; speedup vs baseline: 2.0598x; 2.0598x over previous
//
#include <hip/hip_runtime.h>
#include <math.h>

#define EPSF 1e-8f
#define LOG2E 1.44269504f

typedef short short8 __attribute__((ext_vector_type(8)));
typedef float floatx4 __attribute__((ext_vector_type(4)));

__device__ __forceinline__ unsigned short f2bf(float f) {
    unsigned u = __builtin_bit_cast(unsigned, f);
    unsigned r = (u + 0x7FFFu + ((u >> 16) & 1u)) >> 16;   // RNE
    return (unsigned short)r;
}
__device__ __forceinline__ float bf2f(unsigned short h) {
    return __builtin_bit_cast(float, ((unsigned)h) << 16);
}

// Raw v_exp_f32 where available: args are always <= 0, and weights below 2^-126
// are ~0 either way, so libm's denorm-fixup wrapper is dead weight.
__device__ __forceinline__ float fast_exp2(float x) {
#if __has_builtin(__builtin_amdgcn_exp2f)
    return __builtin_amdgcn_exp2f(x);
#else
    return exp2f(x);
#endif
}

// ---- Prep (one launch, no atomics):
//  blocks 0..31          : train -> bf16 hi/lo + tnorm
//  blocks 32..32+m/256-1 : qn (query norms)
//  last block            : column stats + Scott finalize -> sCws
// R11 lesson: the stats block MUST be load-parallel. Layout here: thread
// (drow=tid>>3, dq=tid&7) strides rows by 32 with float4 loads (coalesced,
// 256 iters, 8 independent fp64 chains) -- ~3 us vs R11's 265 us serial version.
__global__ __launch_bounds__(256) void prep_kernel(const float* __restrict__ x,
                                                   const float* __restrict__ train,
                                                   int n, int m,
                                                   float* __restrict__ tnorm,
                                                   float* __restrict__ qn,
                                                   unsigned short* __restrict__ thi,
                                                   unsigned short* __restrict__ tlo,
                                                   float* __restrict__ sCws) {
    int tid = threadIdx.x;
    int b = blockIdx.x;
    if (b < 32) {
        int rowsPerBlock = n >> 5;          // 256
        int rbase = b * rowsPerBlock;
        for (int r = rbase + tid; r < rbase + rowsPerBlock; r += 256) {
            const float4* row = (const float4*)(train + (size_t)r * 32);
            float s = 0.f;
#pragma unroll
            for (int kb = 0; kb < 4; ++kb) {
                float4 f0 = row[kb * 2], f1 = row[kb * 2 + 1];
                float fv[8] = {f0.x, f0.y, f0.z, f0.w, f1.x, f1.y, f1.z, f1.w};
                short8 h, l;
#pragma unroll
                for (int j = 0; j < 8; ++j) {
                    unsigned short hb = f2bf(fv[j]);
                    h[j] = (short)hb;
                    l[j] = (short)f2bf(fv[j] - bf2f(hb));
                    s = fmaf(fv[j], fv[j], s);
                }
                *(short8*)(thi + (size_t)r * 32 + kb * 8) = h;
                *(short8*)(tlo + (size_t)r * 32 + kb * 8) = l;
            }
            tnorm[r] = s;
        }
    } else {
        int r = (b - 32) * 256 + tid;
        if (r < m) {
            const float4* row = (const float4*)(x + (size_t)r * 32);
            float s = 0.f;
#pragma unroll
            for (int k = 0; k < 8; ++k) {
                float4 t = row[k];
                s = fmaf(t.x, t.x, s); s = fmaf(t.y, t.y, s);
                s = fmaf(t.z, t.z, s); s = fmaf(t.w, t.w, s);
            }
            qn[r] = s;
        } else if (b == (int)gridDim.x - 1) {
            // ---- dedicated Scott block: load-parallel column stats ----
            __shared__ double s1s[256][4];
            __shared__ double s2s[256][4];
            __shared__ float sdv[32];
            int drow = tid >> 3;            // 0..31 row-group
            int dq   = tid & 7;             // 0..7  -> dims dq*4..dq*4+3
            double s1[4] = {0.0, 0.0, 0.0, 0.0};
            double s2[4] = {0.0, 0.0, 0.0, 0.0};
            for (int r2 = drow; r2 < n; r2 += 32) {
                float4 v = *(const float4*)(train + (size_t)r2 * 32 + dq * 4);
                double vx = v.x, vy = v.y, vz = v.z, vw = v.w;
                s1[0] += vx; s2[0] += vx * vx;
                s1[1] += vy; s2[1] += vy * vy;
                s1[2] += vz; s2[2] += vz * vz;
                s1[3] += vw; s2[3] += vw * vw;
            }
#pragma unroll
            for (int j = 0; j < 4; ++j) { s1s[tid][j] = s1[j]; s2s[tid][j] = s2[j]; }
            __syncthreads();
            if (tid < 32) {                 // tid = dim
                int dq2 = tid >> 2, j2 = tid & 3;
                double a = 0.0, c2 = 0.0;
                for (int g = 0; g < 32; ++g) {
                    a  += s1s[g * 8 + dq2][j2];
                    c2 += s2s[g * 8 + dq2][j2];
                }
                double var = (c2 - a * a / (double)n) / (double)(n - 1);  // ddof=1
                sdv[tid] = (float)sqrt(var);
            }
            __syncthreads();
            if (tid == 0) {
                float ms = 0.f;
                for (int k = 0; k < 32; ++k) ms += sdv[k];
                ms *= (1.0f / 32.0f);
                float bw = ms * powf((float)n, -1.0f / 36.0f);
                float c = 1.0f / (2.0f * bw * bw);
                sCws[0] = -c * LOG2E;        // negcl
                sCws[1] = 2.0f * c * LOG2E;  // C2
            }
        }
    }
}

// ---- KDE via MFMA: 2-term bf16 split, M=32/wave, N-tiles of 16, K=32 in one MFMA ----
// R7-proven form (49.2 us): scalar epilogue, unroll 4, launch_bounds(256,8), VGPR 32.
__global__ __launch_bounds__(256, 8) void kde_kernel(const float* __restrict__ x,
                                                     const unsigned short* __restrict__ thi,
                                                     const unsigned short* __restrict__ tlo,
                                                     const float* __restrict__ resid,
                                                     const float* __restrict__ tnorm,
                                                     const float* __restrict__ qn,
                                                     const float* __restrict__ sCws,
                                                     int m, int n, int nchunks,
                                                     float* __restrict__ numP,
                                                     float* __restrict__ denP) {
    int tid = threadIdx.x;
    float negcl = sCws[0], C2 = sCws[1];   // uniform -> scalar loads

    int lane = tid & 63;
    int wave = tid >> 6;
    int col = lane & 15;      // A m-index / B n-index / D col
    int quad = lane >> 4;     // D rows = quad*4 + r
    int Mbase = blockIdx.x * 128 + wave * 32;
    int chunk = n / nchunks;
    int Nstart = blockIdx.y * chunk;

    // --- A fragments: queries prescaled by C2 -> bf16 hi/lo, kept in VGPRs ---
    short8 ah[2], al[2];
#pragma unroll
    for (int s = 0; s < 2; ++s) {
        const float* xp = x + (size_t)(Mbase + s * 16 + col) * 32 + quad * 8;
        float4 f0 = *(const float4*)xp;
        float4 f1 = *(const float4*)(xp + 4);
        float fv[8] = {f0.x, f0.y, f0.z, f0.w, f1.x, f1.y, f1.z, f1.w};
#pragma unroll
        for (int j = 0; j < 8; ++j) {
            float v = fv[j] * C2;
            unsigned short hb = f2bf(v);
            ah[s][j] = (short)hb;
            al[s][j] = (short)f2bf(v - bf2f(hb));
        }
    }

    // --- per-row log2-domain query-norm term ---
    float alpha[2][4];
#pragma unroll
    for (int s = 0; s < 2; ++s)
#pragma unroll
        for (int r = 0; r < 4; ++r)
            alpha[s][r] = negcl * qn[Mbase + s * 16 + quad * 4 + r];

    float num[2][4] = {{0.f, 0.f, 0.f, 0.f}, {0.f, 0.f, 0.f, 0.f}};
    float den[2][4] = {{0.f, 0.f, 0.f, 0.f}, {0.f, 0.f, 0.f, 0.f}};

#pragma unroll 4
    for (int t = 0; t < chunk; t += 16) {
        int row = Nstart + t + col;
        const short8 bh = *(const short8*)(thi + (size_t)row * 32 + quad * 8);
        const short8 bl = *(const short8*)(tlo + (size_t)row * 32 + quad * 8);
        float beta = negcl * tnorm[row];   // per-col (lane) train-norm term
        float rv = resid[row];

#pragma unroll
        for (int s = 0; s < 2; ++s) {
            floatx4 acc = {alpha[s][0] + beta, alpha[s][1] + beta,
                           alpha[s][2] + beta, alpha[s][3] + beta};
            acc = __builtin_amdgcn_mfma_f32_16x16x32_bf16(ah[s], bh, acc, 0, 0, 0);
            acc = __builtin_amdgcn_mfma_f32_16x16x32_bf16(ah[s], bl, acc, 0, 0, 0);
            acc = __builtin_amdgcn_mfma_f32_16x16x32_bf16(al[s], bh, acc, 0, 0, 0);
#pragma unroll
            for (int r = 0; r < 4; ++r) {
                float w = fast_exp2(acc[r]);   // arg == acc (log2 domain)
                num[s][r] = fmaf(w, rv, num[s][r]);
                den[s][r] += w;
            }
        }
    }

    // --- reduce across the 16 lanes sharing each row set (xor 1,2,4,8) ---
#pragma unroll
    for (int s = 0; s < 2; ++s)
#pragma unroll
        for (int r = 0; r < 4; ++r) {
#pragma unroll
            for (int msk = 1; msk < 16; msk <<= 1) {
                num[s][r] += __shfl_xor(num[s][r], msk);
                den[s][r] += __shfl_xor(den[s][r], msk);
            }
        }
    if (col == 0) {
#pragma unroll
        for (int s = 0; s < 2; ++s)
#pragma unroll
            for (int r = 0; r < 4; ++r) {
                int q = Mbase + s * 16 + quad * 4 + r;
                numP[(size_t)blockIdx.y * m + q] = num[s][r];
                denP[(size_t)blockIdx.y * m + q] = den[s][r];
            }
    }
}

// ---- Reduce partials -> rx; per-block min/max of rx & sigma (wave-shuffle version) ----
__global__ __launch_bounds__(256) void reduce_kernel(const float* __restrict__ numP,
                                                     const float* __restrict__ denP,
                                                     const float* __restrict__ sigma,
                                                     float* __restrict__ rxbuf,
                                                     float* __restrict__ bred,
                                                     int m, int nchunks, int nb) {
    __shared__ float wred[4][4];   // [quantity][wave]
    int tid = threadIdx.x;
    int q = blockIdx.x * 256 + tid;

    float num = 0.f, den = 0.f;
    for (int s = 0; s < nchunks; ++s) {
        num += numP[(size_t)s * m + q];
        den += denP[(size_t)s * m + q];
    }
    float rx = num / (den + EPSF);
    rxbuf[q] = rx;
    float sg = sigma[q];

    float rmin = rx, rmax = rx, smin = sg, smax = sg;
#pragma unroll
    for (int o = 32; o > 0; o >>= 1) {
        rmin = fminf(rmin, __shfl_xor(rmin, o));
        rmax = fmaxf(rmax, __shfl_xor(rmax, o));
        smin = fminf(smin, __shfl_xor(smin, o));
        smax = fmaxf(smax, __shfl_xor(smax, o));
    }
    int wave = tid >> 6;
    if ((tid & 63) == 0) {
        wred[0][wave] = rmin; wred[1][wave] = rmax;
        wred[2][wave] = smin; wred[3][wave] = smax;
    }
    __syncthreads();
    if (tid == 0) {
        bred[0 * nb + blockIdx.x] = fminf(fminf(wred[0][0], wred[0][1]), fminf(wred[0][2], wred[0][3]));
        bred[1 * nb + blockIdx.x] = fmaxf(fmaxf(wred[1][0], wred[1][1]), fmaxf(wred[1][2], wred[1][3]));
        bred[2 * nb + blockIdx.x] = fminf(fminf(wred[2][0], wred[2][1]), fminf(wred[2][2], wred[2][3]));
        bred[3 * nb + blockIdx.x] = fmaxf(fmaxf(wred[3][0], wred[3][1]), fmaxf(wred[3][2], wred[3][3]));
    }
}

// ---- Combine: each block redundantly reduces the 64 block-extrema, then writes slice ----
__global__ __launch_bounds__(256) void combine_kernel(const float* __restrict__ rxbuf,
                                                      const float* __restrict__ sigma,
                                                      const float* __restrict__ bred,
                                                      float* __restrict__ out,
                                                      int m, int nb) {
    __shared__ float sc[4];
    int tid = threadIdx.x;
    if (tid < 64) {
        float v0 = (tid < nb) ? bred[0 * nb + tid] : INFINITY;
        float v1 = (tid < nb) ? bred[1 * nb + tid] : -INFINITY;
        float v2 = (tid < nb) ? bred[2 * nb + tid] : INFINITY;
        float v3 = (tid < nb) ? bred[3 * nb + tid] : -INFINITY;
        for (int o = 32; o > 0; o >>= 1) {
            v0 = fminf(v0, __shfl_xor(v0, o));
            v1 = fmaxf(v1, __shfl_xor(v1, o));
            v2 = fminf(v2, __shfl_xor(v2, o));
            v3 = fmaxf(v3, __shfl_xor(v3, o));
        }
        if (tid == 0) {
            sc[0] = v0;
            sc[1] = 1.0f / (v1 - v0 + EPSF);
            sc[2] = v2;
            sc[3] = 1.0f / (v3 - v2 + EPSF);
        }
    }
    __syncthreads();
    int q = blockIdx.x * 256 + tid;
    if (q >= m) return;
    float t1 = 0.5f * (rxbuf[q] - sc[0]) * sc[1];
    float t2 = 0.5f * (sigma[q] - sc[2]) * sc[3];
    out[q] = t1 + t2;
}

extern "C" void kernel_launch(void* const* d_in, const int* in_sizes, int n_in,
                              void* d_out, int out_size, void* d_ws, size_t ws_size,
                              hipStream_t stream) {
    const float* x     = (const float*)d_in[0];  // [m, 32]
    const float* train = (const float*)d_in[1];  // [n, 32]
    const float* resid = (const float*)d_in[2];  // [n]
    const float* sigma = (const float*)d_in[3];  // [m]
    float* out = (float*)d_out;

    int n = in_sizes[2];   // 8192
    int m = in_sizes[3];   // 16384
    int nb = m / 256;      // 64

    // ws layout: fp32 arrays, scalar block, bf16 arrays, partials
    float*  tnorm = (float*)d_ws;                   // n
    float*  qn    = tnorm + n;                      // m
    float*  rxbuf = qn + m;                         // m
    float*  bred  = rxbuf + m;                      // 4*nb
    float*  sCws  = bred + 4 * nb;                  // 2 floats + 2 pad
    unsigned short* thi = (unsigned short*)(sCws + 4);       // n*32
    unsigned short* tlo = thi + (size_t)n * 32;              // n*32
    float* numP = (float*)(tlo + (size_t)n * 32);
    size_t baseBytes = (size_t)((char*)numP - (char*)d_ws);

    int nchunks = 16;
    while (nchunks > 1 &&
           baseBytes + (size_t)2 * nchunks * m * sizeof(float) > ws_size)
        nchunks >>= 1;
    float* denP = numP + (size_t)nchunks * m;

    // 4 stream ops total
    int nqb = (m + 255) / 256;
    prep_kernel<<<32 + nqb + 1, 256, 0, stream>>>(x, train, n, m, tnorm, qn,
                                                  thi, tlo, sCws);

    dim3 grid_c(m / 128, nchunks);   // 4 waves/block, M=32 per wave; 2048 blocks = 8/CU resident
    kde_kernel<<<grid_c, 256, 0, stream>>>(x, thi, tlo, resid, tnorm, qn,
                                           sCws, m, n, nchunks, numP, denP);

    reduce_kernel<<<nb, 256, 0, stream>>>(numP, denP, sigma, rxbuf, bred, m, nchunks, nb);
    combine_kernel<<<nb, 256, 0, stream>>>(rxbuf, sigma, bred, out, m, nb);
}

// Round 13
// 119.672 us; speedup vs baseline: 3.0940x; 1.5021x over previous
//
#include <hip/hip_runtime.h>
#include <math.h>

#define EPSF 1e-8f
#define LOG2E 1.44269504f

typedef short short8 __attribute__((ext_vector_type(8)));
typedef float floatx4 __attribute__((ext_vector_type(4)));

__device__ __forceinline__ unsigned short f2bf(float f) {
    unsigned u = __builtin_bit_cast(unsigned, f);
    unsigned r = (u + 0x7FFFu + ((u >> 16) & 1u)) >> 16;   // RNE
    return (unsigned short)r;
}
__device__ __forceinline__ float bf2f(unsigned short h) {
    return __builtin_bit_cast(float, ((unsigned)h) << 16);
}

// Raw v_exp_f32 where available: args are always <= 0, and weights below 2^-126
// are ~0 either way, so libm's denorm-fixup wrapper is dead weight.
__device__ __forceinline__ float fast_exp2(float x) {
#if __has_builtin(__builtin_amdgcn_exp2f)
    return __builtin_amdgcn_exp2f(x);
#else
    return exp2f(x);
#endif
}

// ---- Prep: blocks 0..31: train bf16 hi/lo + tnorm + stats partials; blocks 32..: qn ----
// (R6-proven form: stats distributed across the 32 staging blocks -- R11/R12's
// centralized one-block stats hit the single-CU L2 floor and straggled prep.)
__global__ __launch_bounds__(256) void prep_kernel(const float* __restrict__ x,
                                                   const float* __restrict__ train,
                                                   int n, int m,
                                                   float* __restrict__ tnorm,
                                                   float* __restrict__ qn,
                                                   unsigned short* __restrict__ thi,
                                                   unsigned short* __restrict__ tlo,
                                                   double* __restrict__ pS1,
                                                   double* __restrict__ pS2) {
    int tid = threadIdx.x;
    int b = blockIdx.x;
    if (b < 32) {
        __shared__ double s1s[256];
        __shared__ double s2s[256];
        int rowsPerBlock = n >> 5;          // 256
        int rbase = b * rowsPerBlock;
        for (int r = rbase + tid; r < rbase + rowsPerBlock; r += 256) {
            const float4* row = (const float4*)(train + (size_t)r * 32);
            float s = 0.f;
#pragma unroll
            for (int kb = 0; kb < 4; ++kb) {
                float4 f0 = row[kb * 2], f1 = row[kb * 2 + 1];
                float fv[8] = {f0.x, f0.y, f0.z, f0.w, f1.x, f1.y, f1.z, f1.w};
                short8 h, l;
#pragma unroll
                for (int j = 0; j < 8; ++j) {
                    unsigned short hb = f2bf(fv[j]);
                    h[j] = (short)hb;
                    l[j] = (short)f2bf(fv[j] - bf2f(hb));
                    s = fmaf(fv[j], fv[j], s);
                }
                *(short8*)(thi + (size_t)r * 32 + kb * 8) = h;
                *(short8*)(tlo + (size_t)r * 32 + kb * 8) = l;
            }
            tnorm[r] = s;
        }
        // stats partials (column sums, fp64)
        int dim = tid & 31;
        int grp = tid >> 5;
        int rpt = rowsPerBlock >> 3;
        int r0 = rbase + grp * rpt;
        double s1 = 0.0, s2 = 0.0;
        for (int i = 0; i < rpt; ++i) {
            float v = train[(size_t)(r0 + i) * 32 + dim];
            s1 += (double)v;
            s2 += (double)v * (double)v;
        }
        s1s[tid] = s1;
        s2s[tid] = s2;
        __syncthreads();
        if (tid < 32) {
            double a = 0.0, c2 = 0.0;
            for (int g = 0; g < 8; ++g) { a += s1s[g * 32 + tid]; c2 += s2s[g * 32 + tid]; }
            pS1[b * 32 + tid] = a;
            pS2[b * 32 + tid] = c2;
        }
    } else {
        int r = (b - 32) * 256 + tid;
        if (r < m) {
            const float4* row = (const float4*)(x + (size_t)r * 32);
            float s = 0.f;
#pragma unroll
            for (int k = 0; k < 8; ++k) {
                float4 t = row[k];
                s = fmaf(t.x, t.x, s); s = fmaf(t.y, t.y, s);
                s = fmaf(t.z, t.z, s); s = fmaf(t.w, t.w, s);
            }
            qn[r] = s;
        }
    }
}

// ---- KDE via MFMA: 2-term bf16 split, M=32/wave, N-tiles of 16, K=32 in one MFMA ----
// R6-proven form (best total 119.8 us), single diff: t-loop unroll 2 -> 4 (proven
// bit-identical in R7/R8/R10, part of the best-measured 49.2 us kde).
__global__ __launch_bounds__(256, 8) void kde_kernel(const float* __restrict__ x,
                                                     const unsigned short* __restrict__ thi,
                                                     const unsigned short* __restrict__ tlo,
                                                     const float* __restrict__ resid,
                                                     const float* __restrict__ tnorm,
                                                     const float* __restrict__ qn,
                                                     const double* __restrict__ pS1,
                                                     const double* __restrict__ pS2,
                                                     int m, int n, int nchunks,
                                                     float* __restrict__ numP,
                                                     float* __restrict__ denP) {
    __shared__ double sred[32];
    __shared__ float sC[2];   // negcl, C2
    int tid = threadIdx.x;

    // --- Scott's rule prologue (per block; pS1/pS2 are tiny and L2-hot) ---
    if (tid < 32) {
        double a = 0.0, b2 = 0.0;
        for (int k = 0; k < 32; ++k) { a += pS1[k * 32 + tid]; b2 += pS2[k * 32 + tid]; }
        double var = (b2 - a * a / (double)n) / (double)(n - 1);  // ddof=1
        sred[tid] = sqrt(var);
    }
    __syncthreads();
    if (tid == 0) {
        float ms = 0.f;
        for (int k = 0; k < 32; ++k) ms += (float)sred[k];
        ms *= (1.0f / 32.0f);
        float bw = ms * powf((float)n, -1.0f / 36.0f);
        float c = 1.0f / (2.0f * bw * bw);
        sC[0] = -c * LOG2E;        // negcl
        sC[1] = 2.0f * c * LOG2E;  // C2
    }
    __syncthreads();
    float negcl = sC[0], C2 = sC[1];

    int lane = tid & 63;
    int wave = tid >> 6;
    int col = lane & 15;      // A m-index / B n-index / D col
    int quad = lane >> 4;     // D rows = quad*4 + r
    int Mbase = blockIdx.x * 128 + wave * 32;
    int chunk = n / nchunks;
    int Nstart = blockIdx.y * chunk;

    // --- A fragments: queries prescaled by C2 -> bf16 hi/lo, kept in VGPRs ---
    short8 ah[2], al[2];
#pragma unroll
    for (int s = 0; s < 2; ++s) {
        const float* xp = x + (size_t)(Mbase + s * 16 + col) * 32 + quad * 8;
        float4 f0 = *(const float4*)xp;
        float4 f1 = *(const float4*)(xp + 4);
        float fv[8] = {f0.x, f0.y, f0.z, f0.w, f1.x, f1.y, f1.z, f1.w};
#pragma unroll
        for (int j = 0; j < 8; ++j) {
            float v = fv[j] * C2;
            unsigned short hb = f2bf(v);
            ah[s][j] = (short)hb;
            al[s][j] = (short)f2bf(v - bf2f(hb));
        }
    }

    // --- per-row log2-domain query-norm term ---
    float alpha[2][4];
#pragma unroll
    for (int s = 0; s < 2; ++s)
#pragma unroll
        for (int r = 0; r < 4; ++r)
            alpha[s][r] = negcl * qn[Mbase + s * 16 + quad * 4 + r];

    float num[2][4] = {{0.f, 0.f, 0.f, 0.f}, {0.f, 0.f, 0.f, 0.f}};
    float den[2][4] = {{0.f, 0.f, 0.f, 0.f}, {0.f, 0.f, 0.f, 0.f}};

#pragma unroll 4
    for (int t = 0; t < chunk; t += 16) {
        int row = Nstart + t + col;
        const short8 bh = *(const short8*)(thi + (size_t)row * 32 + quad * 8);
        const short8 bl = *(const short8*)(tlo + (size_t)row * 32 + quad * 8);
        float beta = negcl * tnorm[row];   // per-col (lane) train-norm term
        float rv = resid[row];

#pragma unroll
        for (int s = 0; s < 2; ++s) {
            floatx4 acc = {alpha[s][0] + beta, alpha[s][1] + beta,
                           alpha[s][2] + beta, alpha[s][3] + beta};
            acc = __builtin_amdgcn_mfma_f32_16x16x32_bf16(ah[s], bh, acc, 0, 0, 0);
            acc = __builtin_amdgcn_mfma_f32_16x16x32_bf16(ah[s], bl, acc, 0, 0, 0);
            acc = __builtin_amdgcn_mfma_f32_16x16x32_bf16(al[s], bh, acc, 0, 0, 0);
#pragma unroll
            for (int r = 0; r < 4; ++r) {
                float w = fast_exp2(acc[r]);   // arg == acc (log2 domain)
                num[s][r] = fmaf(w, rv, num[s][r]);
                den[s][r] += w;
            }
        }
    }

    // --- reduce across the 16 lanes sharing each row set (xor 1,2,4,8) ---
#pragma unroll
    for (int s = 0; s < 2; ++s)
#pragma unroll
        for (int r = 0; r < 4; ++r) {
#pragma unroll
            for (int msk = 1; msk < 16; msk <<= 1) {
                num[s][r] += __shfl_xor(num[s][r], msk);
                den[s][r] += __shfl_xor(den[s][r], msk);
            }
        }
    if (col == 0) {
#pragma unroll
        for (int s = 0; s < 2; ++s)
#pragma unroll
            for (int r = 0; r < 4; ++r) {
                int q = Mbase + s * 16 + quad * 4 + r;
                numP[(size_t)blockIdx.y * m + q] = num[s][r];
                denP[(size_t)blockIdx.y * m + q] = den[s][r];
            }
    }
}

// ---- Reduce partials -> rx; per-block min/max of rx & sigma (wave-shuffle version) ----
__global__ __launch_bounds__(256) void reduce_kernel(const float* __restrict__ numP,
                                                     const float* __restrict__ denP,
                                                     const float* __restrict__ sigma,
                                                     float* __restrict__ rxbuf,
                                                     float* __restrict__ bred,
                                                     int m, int nchunks, int nb) {
    __shared__ float wred[4][4];   // [quantity][wave]
    int tid = threadIdx.x;
    int q = blockIdx.x * 256 + tid;

    float num = 0.f, den = 0.f;
    for (int s = 0; s < nchunks; ++s) {
        num += numP[(size_t)s * m + q];
        den += denP[(size_t)s * m + q];
    }
    float rx = num / (den + EPSF);
    rxbuf[q] = rx;
    float sg = sigma[q];

    float rmin = rx, rmax = rx, smin = sg, smax = sg;
#pragma unroll
    for (int o = 32; o > 0; o >>= 1) {
        rmin = fminf(rmin, __shfl_xor(rmin, o));
        rmax = fmaxf(rmax, __shfl_xor(rmax, o));
        smin = fminf(smin, __shfl_xor(smin, o));
        smax = fmaxf(smax, __shfl_xor(smax, o));
    }
    int wave = tid >> 6;
    if ((tid & 63) == 0) {
        wred[0][wave] = rmin; wred[1][wave] = rmax;
        wred[2][wave] = smin; wred[3][wave] = smax;
    }
    __syncthreads();
    if (tid == 0) {
        bred[0 * nb + blockIdx.x] = fminf(fminf(wred[0][0], wred[0][1]), fminf(wred[0][2], wred[0][3]));
        bred[1 * nb + blockIdx.x] = fmaxf(fmaxf(wred[1][0], wred[1][1]), fmaxf(wred[1][2], wred[1][3]));
        bred[2 * nb + blockIdx.x] = fminf(fminf(wred[2][0], wred[2][1]), fminf(wred[2][2], wred[2][3]));
        bred[3 * nb + blockIdx.x] = fmaxf(fmaxf(wred[3][0], wred[3][1]), fmaxf(wred[3][2], wred[3][3]));
    }
}

// ---- Combine: each block redundantly reduces the 64 block-extrema, then writes slice ----
__global__ __launch_bounds__(256) void combine_kernel(const float* __restrict__ rxbuf,
                                                      const float* __restrict__ sigma,
                                                      const float* __restrict__ bred,
                                                      float* __restrict__ out,
                                                      int m, int nb) {
    __shared__ float sc[4];
    int tid = threadIdx.x;
    if (tid < 64) {
        float v0 = (tid < nb) ? bred[0 * nb + tid] : INFINITY;
        float v1 = (tid < nb) ? bred[1 * nb + tid] : -INFINITY;
        float v2 = (tid < nb) ? bred[2 * nb + tid] : INFINITY;
        float v3 = (tid < nb) ? bred[3 * nb + tid] : -INFINITY;
        for (int o = 32; o > 0; o >>= 1) {
            v0 = fminf(v0, __shfl_xor(v0, o));
            v1 = fmaxf(v1, __shfl_xor(v1, o));
            v2 = fminf(v2, __shfl_xor(v2, o));
            v3 = fmaxf(v3, __shfl_xor(v3, o));
        }
        if (tid == 0) {
            sc[0] = v0;
            sc[1] = 1.0f / (v1 - v0 + EPSF);
            sc[2] = v2;
            sc[3] = 1.0f / (v3 - v2 + EPSF);
        }
    }
    __syncthreads();
    int q = blockIdx.x * 256 + tid;
    if (q >= m) return;
    float t1 = 0.5f * (rxbuf[q] - sc[0]) * sc[1];
    float t2 = 0.5f * (sigma[q] - sc[2]) * sc[3];
    out[q] = t1 + t2;
}

extern "C" void kernel_launch(void* const* d_in, const int* in_sizes, int n_in,
                              void* d_out, int out_size, void* d_ws, size_t ws_size,
                              hipStream_t stream) {
    const float* x     = (const float*)d_in[0];  // [m, 32]
    const float* train = (const float*)d_in[1];  // [n, 32]
    const float* resid = (const float*)d_in[2];  // [n]
    const float* sigma = (const float*)d_in[3];  // [m]
    float* out = (float*)d_out;

    int n = in_sizes[2];   // 8192
    int m = in_sizes[3];   // 16384
    int nb = m / 256;      // 64

    // ws layout: fp64 first, then fp32, then bf16 arrays, then partials
    double* pS1   = (double*)d_ws;                  // 32*32
    double* pS2   = pS1 + 1024;                     // 32*32
    float*  tnorm = (float*)(pS2 + 1024);           // n
    float*  qn    = tnorm + n;                      // m
    float*  rxbuf = qn + m;                         // m
    float*  bred  = rxbuf + m;                      // 4*nb
    unsigned short* thi = (unsigned short*)(bred + 4 * nb);  // n*32
    unsigned short* tlo = thi + (size_t)n * 32;              // n*32
    float* numP = (float*)(tlo + (size_t)n * 32);
    size_t baseBytes = (size_t)((char*)numP - (char*)d_ws);

    int nchunks = 16;
    while (nchunks > 1 &&
           baseBytes + (size_t)2 * nchunks * m * sizeof(float) > ws_size)
        nchunks >>= 1;
    float* denP = numP + (size_t)nchunks * m;

    prep_kernel<<<32 + (m + 255) / 256, 256, 0, stream>>>(x, train, n, m, tnorm, qn,
                                                          thi, tlo, pS1, pS2);

    dim3 grid_c(m / 128, nchunks);   // 4 waves/block, M=32 per wave; 2048 blocks = 8/CU resident
    kde_kernel<<<grid_c, 256, 0, stream>>>(x, thi, tlo, resid, tnorm, qn,
                                           pS1, pS2, m, n, nchunks, numP, denP);

    reduce_kernel<<<nb, 256, 0, stream>>>(numP, denP, sigma, rxbuf, bred, m, nchunks, nb);
    combine_kernel<<<nb, 256, 0, stream>>>(rxbuf, sigma, bred, out, m, nb);
}